// Round 17
// baseline (772.995 us; speedup 1.0000x reference)
//
#include <hip/hip_runtime.h>

#define NN 50000
#define NE 400000
#define DIM 128

typedef __bf16 bf16x8 __attribute__((ext_vector_type(8)));
typedef float f32x4 __attribute__((ext_vector_type(4)));
typedef unsigned short u16;

#define MFMA16 __builtin_amdgcn_mfma_f32_16x16x32_bf16

__device__ __forceinline__ u16 f2b(float f){ __bf16 b=(__bf16)f; return __builtin_bit_cast(u16,b); }
__device__ __forceinline__ float b2f(u16 h){ unsigned u = ((unsigned)h)<<16; return __builtin_bit_cast(float,u); }
__device__ __forceinline__ float sigm(float x){ return 1.0f/(1.0f+__expf(-x)); }
__device__ __forceinline__ float tanh_(float x){ float e=__expf(2.0f*x); return 1.0f-2.0f/(e+1.0f); }
__device__ __forceinline__ bf16x8 ldb8(const u16* p){ return *reinterpret_cast<const bf16x8*>(p); }

#define GLOAD_LDS(gp, lp) __builtin_amdgcn_global_load_lds( \
    (const __attribute__((address_space(1))) void*)(gp),    \
    (__attribute__((address_space(3))) void*)(lp), 16, 0, 0)

// ---------- utility kernels ----------
__global__ void f2b_kernel(const float* __restrict__ in, u16* __restrict__ out, int n4){
  int i = blockIdx.x*blockDim.x + threadIdx.x;
  int st = gridDim.x*blockDim.x;
  for (; i<n4; i+=st){
    float4 v = reinterpret_cast<const float4*>(in)[i];
    ushort4 o = { f2b(v.x), f2b(v.y), f2b(v.z), f2b(v.w) };
    reinterpret_cast<ushort4*>(out)[i] = o;
  }
}

// fused weight prep: all 4 GRU weight converts + aW1 transpose in one launch
__global__ void wprep_kernel(const float* __restrict__ eWih, const float* __restrict__ eWhh,
                             const float* __restrict__ nWih, const float* __restrict__ nWhh,
                             const float* __restrict__ aW1,
                             u16* __restrict__ bWih, u16* __restrict__ bWhh,
                             u16* __restrict__ bnWih, u16* __restrict__ bnWhh,
                             u16* __restrict__ baW1T){
  int i = blockIdx.x*256 + threadIdx.x;        // 1024 blocks x 256 = 262144
  if (i < 98304){ bWih[i] = f2b(eWih[i]); return; }
  i -= 98304;
  if (i < 49152){ bWhh[i] = f2b(eWhh[i]); return; }
  i -= 49152;
  if (i < 49152){ bnWih[i] = f2b(nWih[i]); return; }
  i -= 49152;
  if (i < 49152){ bnWhh[i] = f2b(nWhh[i]); return; }
  i -= 49152;
  { int k = i>>7, n = i&127; baW1T[n*128+k] = f2b(aW1[i]); }
}

__global__ void hist_kernel(const int* __restrict__ dst, int* __restrict__ counts, int n){
  int i = blockIdx.x*blockDim.x + threadIdx.x; if (i<n) atomicAdd(&counts[dst[i]],1);
}
// parallel exclusive scan over counts -> rowp/cursor (3 phases)
__global__ void scanA_kernel(const int* __restrict__ counts, int* __restrict__ rowp,
                             int* __restrict__ bsum, int n){
  __shared__ int buf[1024];
  const int gid = blockIdx.x*1024 + threadIdx.x;
  int v = (gid<n) ? counts[gid] : 0;
  buf[threadIdx.x]=v; __syncthreads();
  for (int off=1; off<1024; off<<=1){
    int x = (threadIdx.x>=off) ? buf[threadIdx.x-off] : 0;
    __syncthreads();
    buf[threadIdx.x]+=x; __syncthreads();
  }
  if (gid<n) rowp[gid] = buf[threadIdx.x]-v;          // block-local exclusive
  if (threadIdx.x==1023) bsum[blockIdx.x]=buf[1023];  // block total
}
__global__ void scanB_kernel(int* bsum, int* rowp, int nb, int n){
  if (threadIdx.x==0 && blockIdx.x==0){
    int run=0;
    for (int b=0;b<nb;++b){ int t=bsum[b]; bsum[b]=run; run+=t; }
    rowp[n]=run;
  }
}
__global__ void scanC_kernel(int* __restrict__ rowp, int* __restrict__ cursor,
                             const int* __restrict__ bsum, int n){
  const int gid = blockIdx.x*1024 + threadIdx.x;
  if (gid<n){ int v = rowp[gid]+bsum[blockIdx.x]; rowp[gid]=v; cursor[gid]=v; }
}
__global__ void scatter_kernel(const int* __restrict__ dst, int* __restrict__ cursor,
                               int* __restrict__ eids, int n){
  int i = blockIdx.x*blockDim.x + threadIdx.x;
  if (i<n){ int p = atomicAdd(&cursor[dst[i]],1); eids[p]=i; }
}
// permuted edge endpoints (CSR order by dst)
__global__ void perm_kernel(const int* __restrict__ eids, const int* __restrict__ src,
                            const int* __restrict__ dst, int* __restrict__ srcp,
                            int* __restrict__ dstp, int n){
  int i = blockIdx.x*blockDim.x + threadIdx.x;
  if (i<n){ int e=eids[i]; srcp[i]=src[e]; dstp[i]=dst[e]; }
}

// ---------- edge GRU + attention MLP (v17: fused ef ingest, L1-hot h0 both iters) ----------
// v12 hot-loop (converged optimum: 294us): 512 thr = 8 waves x 16 edges, single
// 36KB frag-major weight buffer, 2-barrier chunk loop, launch_bounds(512,4).
// Template<IT0>: it0 gathers ef rows from fp32 ef_in (via eids), converts to
// bf16 ae A-frags AND SEEDS efb with the rows (coalesced 16B stores) before
// stage(0)+barrier (vmcnt(0) drain -> L1-visible). Chunk-loop h0 then reads
// efb L1-hot in BOTH iterations (v16's scattered fp32 h0 cost +28us).
// it1 instantiation remains bit-identical to v12's kernel.
template<bool IT0>
__global__ __launch_bounds__(512, 4)
void edge_kernel(const int* __restrict__ srcp, const int* __restrict__ dstp,
                 const int* __restrict__ eids,
                 const u16* __restrict__ nfb, u16* __restrict__ efb,
                 const float* __restrict__ ef32in,
                 const u16* __restrict__ Wih, const u16* __restrict__ Whh,
                 const float* __restrict__ bih, const float* __restrict__ bhh,
                 const u16* __restrict__ aW1T, const float* __restrict__ ab1,
                 const float* __restrict__ aW2, const float* __restrict__ ab2,
                 float* __restrict__ logits, float* __restrict__ ef32out)
{
  __shared__ __align__(16) u16 wbuf[36*512];   // 36 KB, frag-major
  const int wave = threadIdx.x>>6, lane = threadIdx.x&63;
  const int r16 = lane&15, kq = lane>>4;
  const long base = (long)blockIdx.x*128 + wave*16;
  const long e = base + r16;

  // cooperative staging of chunk c's weight frags (c=8 -> attention weights)
  auto stage = [&](int c){
    if (c < 8){
      for (int f = wave; f < 36; f += 8){
        const u16* g;
        if (f < 24){ const int gt = f>>3, s = f&7;
          g = Wih + (long)(gt*128 + c*16 + r16)*256 + s*32 + kq*8; }
        else { const int q = f-24, gt = q>>2, s = q&3;
          g = Whh + (long)(gt*128 + c*16 + r16)*128 + s*32 + kq*8; }
        GLOAD_LDS(g, wbuf + f*512);
      }
    } else {
      for (int f = wave; f < 32; f += 8){
        const int t = f>>2, s = f&3;
        GLOAD_LDS(aW1T + (long)(t*16 + r16)*128 + s*32 + kq*8, wbuf + f*512);
      }
    }
  };

  // A-fragments, loaded ONCE into registers: gi K=256 (src|dst), gh K=128 (ef)
  const u16* sp = nfb + (long)srcp[e]*DIM;
  const u16* dp = nfb + (long)dstp[e]*DIM;
  u16* ep = efb + e*DIM;
  bf16x8 ag[8], ae[4];
#pragma unroll
  for (int s=0;s<4;++s){
    ag[s]   = ldb8(sp + s*32 + kq*8);
    ag[s+4] = ldb8(dp + s*32 + kq*8);
  }
  if (IT0){
    // gather fp32 ef row (original order), convert, and seed efb (coalesced).
    // Each lane handles a 32-col slice of its own row e at cols kq*8 + s*32.
    const float* epf = ef32in + (long)eids[e]*DIM;
#pragma unroll
    for (int s=0;s<4;++s){
      float4 f0 = *reinterpret_cast<const float4*>(epf + s*32 + kq*8);
      float4 f1 = *reinterpret_cast<const float4*>(epf + s*32 + kq*8 + 4);
      bf16x8 t;
      t[0]=(__bf16)f0.x; t[1]=(__bf16)f0.y; t[2]=(__bf16)f0.z; t[3]=(__bf16)f0.w;
      t[4]=(__bf16)f1.x; t[5]=(__bf16)f1.y; t[6]=(__bf16)f1.z; t[7]=(__bf16)f1.w;
      ae[s] = t;
      *reinterpret_cast<uint4*>(ep + s*32 + kq*8) = __builtin_bit_cast(uint4, t);
    }
  } else {
#pragma unroll
    for (int s=0;s<4;++s) ae[s] = ldb8(ep + s*32 + kq*8);
  }
  // original edge ids for the 4 rows this lane epilogues
  int oe[4];
#pragma unroll
  for (int r=0;r<4;++r) oe[r] = eids[base + kq*4 + r];

  stage(0);
  __syncthreads();   // drains seed stores (vmcnt 0) + stage(0); h0 reads L1-hot

  // hoisted bases: all epilogue accesses are base + r*DIM + c*16 (imm-friendly)
  u16* ebase = efb + (base + kq*4)*DIM + r16;
  const float* bi0 = bih + r16;
  const float* bh0 = bhh + r16;

  const f32x4 vzero = {0.f,0.f,0.f,0.f};
  const u16* lbase = wbuf + lane*8;   // frag f => lbase + f*512 (u16 units)

#pragma unroll 1
  for (int c=0;c<8;++c){
    const int c16 = c*16;
    const float bir=bi0[c16], biz=bi0[c16+DIM], bin=bi0[c16+2*DIM];
    const float bhr=bh0[c16], bhz=bh0[c16+DIM], bhn=bh0[c16+2*DIM];
    float h0p[4];
#pragma unroll
    for (int r=0;r<4;++r) h0p[r] = b2f(ebase[r*DIM + c16]);  // L1/L2-hot (both iters)

    f32x4 ar=vzero, az=vzero, an=vzero, hr=vzero, hz=vzero, hn=vzero;
#pragma unroll
    for (int s=0;s<8;++s){
      ar = MFMA16(ag[s], ldb8(lbase + ( s   )*512), ar,0,0,0);
      az = MFMA16(ag[s], ldb8(lbase + ( 8+s )*512), az,0,0,0);
      an = MFMA16(ag[s], ldb8(lbase + (16+s )*512), an,0,0,0);
    }
#pragma unroll
    for (int s=0;s<4;++s){
      hr = MFMA16(ae[s], ldb8(lbase + (24+s)*512), hr,0,0,0);
      hz = MFMA16(ae[s], ldb8(lbase + (28+s)*512), hz,0,0,0);
      hn = MFMA16(ae[s], ldb8(lbase + (32+s)*512), hn,0,0,0);
    }
    __syncthreads();              // all waves done reading wbuf
    stage(c+1);                   // refill; drains at end-of-chunk barrier
    float uv[4];
#pragma unroll
    for (int r=0;r<4;++r){
      float rg = sigm(ar[r]+bir + hr[r]+bhr);
      float zg = sigm(az[r]+biz + hz[r]+bhz);
      float ng = tanh_(an[r]+bin + rg*(hn[r]+bhn));
      float u  = ng + zg*(h0p[r]-ng);
      ebase[r*DIM + c16] = f2b(u);
      uv[r] = u;
    }
    if (ef32out){
#pragma unroll
      for (int r=0;r<4;++r) ef32out[(long)oe[r]*DIM + c16 + r16] = uv[r];
    }
    __syncthreads();              // wbuf refilled; stores drained
  }

  // ----- attention MLP: chunk 8 (aW1T) in wbuf; uef row re-read L1-hot -----
  bf16x8 ua[4];
#pragma unroll
  for (int s=0;s<4;++s) ua[s] = ldb8(ep + s*32 + kq*8);
  float part[4] = {0.f,0.f,0.f,0.f};
#pragma unroll 1
  for (int t=0;t<8;++t){
    f32x4 h = vzero;
#pragma unroll
    for (int s=0;s<4;++s)
      h = MFMA16(ua[s], ldb8(lbase + (t*4+s)*512), h,0,0,0);
    const int cc = t*16 + r16;
    const float b1 = ab1[cc], w2 = aW2[cc];
#pragma unroll
    for (int r=0;r<4;++r) part[r] += fmaxf(h[r]+b1, 0.f)*w2;
  }
#pragma unroll
  for (int off=1; off<16; off<<=1){
#pragma unroll
    for (int r=0;r<4;++r) part[r] += __shfl_xor(part[r], off, 64);
  }
  if (r16==0){
    const float b2v = ab2[0];
#pragma unroll
    for (int r=0;r<4;++r) logits[base + kq*4 + r] = part[r] + b2v;   // sequential
  }
}

// ---------- softmax + weighted aggregation (permuted CSR: fully sequential) ----------
__global__ __launch_bounds__(256)
void agg_kernel(const int* __restrict__ rowp, const float* __restrict__ logits,
                const u16* __restrict__ uefb, u16* __restrict__ aggb)
{
  const int wave = threadIdx.x>>6, lane = threadIdx.x&63;
  const int v = blockIdx.x*4 + wave;
  if (v>=NN) return;
  const int p0 = rowp[v], p1 = rowp[v+1], deg = p1-p0;
  float ax=0.f, ay=0.f;
  if (deg>0){
    float mx = -__builtin_inff();
    for (int i=p0+lane; i<p1; i+=64) mx = fmaxf(mx, logits[i]);
#pragma unroll
    for (int off=32; off; off>>=1) mx = fmaxf(mx, __shfl_xor(mx, off, 64));
    float ss = 0.f;
    for (int i=p0+lane; i<p1; i+=64) ss += __expf(logits[i] - mx);
#pragma unroll
    for (int off=32; off; off>>=1) ss += __shfl_xor(ss, off, 64);
    const float inv = 1.0f/ss;
    int i = p0;
    for (; i+2<=p1; i+=2){
      const float l0 = logits[i], l1 = logits[i+1];
      const unsigned q0 = *reinterpret_cast<const unsigned*>(uefb + (long)i*DIM + lane*2);
      const unsigned q1 = *reinterpret_cast<const unsigned*>(uefb + (long)(i+1)*DIM + lane*2);
      const float a0 = __expf(l0-mx)*inv, a1 = __expf(l1-mx)*inv;
      ax += a0*b2f((u16)q0) + a1*b2f((u16)q1);
      ay += a0*b2f((u16)(q0>>16)) + a1*b2f((u16)(q1>>16));
    }
    if (i<p1){
      const float a0 = __expf(logits[i]-mx)*inv;
      const unsigned q0 = *reinterpret_cast<const unsigned*>(uefb + (long)i*DIM + lane*2);
      ax += a0*b2f((u16)q0);
      ay += a0*b2f((u16)(q0>>16));
    }
  }
  unsigned pack = (unsigned)f2b(ax) | ((unsigned)f2b(ay)<<16);
  *reinterpret_cast<unsigned*>(aggb + (long)v*DIM + lane*2) = pack;
}

// ---------- node GRU (double-buffered staged weights, 8 waves x 16 nodes) ----------
__global__ __launch_bounds__(512, 4)
void node_kernel(const u16* __restrict__ aggb, u16* __restrict__ nfb,
                 const float* nf32, float* unf32,            // may alias (in-place iter 2)
                 const u16* __restrict__ Wih, const u16* __restrict__ Whh,
                 const float* __restrict__ bih, const float* __restrict__ bhh)
{
  __shared__ __align__(16) u16 wbuf[2*24*512];   // 48 KB, frag-major, double-buffered
  const int wave = threadIdx.x>>6, lane = threadIdx.x&63;
  const int r16 = lane&15, kq = lane>>4;
  const long tbase = (long)blockIdx.x*128 + wave*16;
  const long v = tbase + r16;
  const long vcl = (v < NN) ? v : (NN-1);

  auto stage = [&](int c){
    if (c >= 8) return;
    u16* bufp = wbuf + (c&1)*24*512;
    for (int f = wave; f < 24; f += 8){
      const u16* g;
      if (f < 12){ const int gt = f>>2, s = f&3;
        g = Wih + (long)(gt*128 + c*16 + r16)*128 + s*32 + kq*8; }
      else { const int q = f-12, gt = q>>2, s = q&3;
        g = Whh + (long)(gt*128 + c*16 + r16)*128 + s*32 + kq*8; }
      GLOAD_LDS(g, bufp + f*512);
    }
  };

  bf16x8 xa[4], ha[4];
#pragma unroll
  for (int s=0;s<4;++s){
    xa[s] = ldb8(aggb + vcl*DIM + s*32 + kq*8);
    ha[s] = ldb8(nfb  + vcl*DIM + s*32 + kq*8);
  }
  stage(0);
  __syncthreads();

  const f32x4 vzero = {0.f,0.f,0.f,0.f};

#pragma unroll 1
  for (int c=0;c<8;++c){
    stage(c+1);
    const int oc = c*16 + r16;
    const float bir=bih[oc], biz=bih[DIM+oc], bin=bih[2*DIM+oc];
    const float bhr=bhh[oc], bhz=bhh[DIM+oc], bhn=bhh[2*DIM+oc];
    float h0p[4];
#pragma unroll
    for (int r=0;r<4;++r){
      const long rr = tbase + kq*4 + r;
      h0p[r] = (rr < NN) ? nf32[rr*DIM+oc] : 0.f;
    }
    const u16* lb = wbuf + (c&1)*24*512 + lane*8;
    f32x4 ar=vzero, az=vzero, an=vzero, hr=vzero, hz=vzero, hn=vzero;
#pragma unroll
    for (int s=0;s<4;++s){
      ar=MFMA16(xa[s], ldb8(lb + ( s   )*512), ar,0,0,0);
      az=MFMA16(xa[s], ldb8(lb + ( 4+s)*512), az,0,0,0);
      an=MFMA16(xa[s], ldb8(lb + ( 8+s)*512), an,0,0,0);
      hr=MFMA16(ha[s], ldb8(lb + (12+s)*512), hr,0,0,0);
      hz=MFMA16(ha[s], ldb8(lb + (16+s)*512), hz,0,0,0);
      hn=MFMA16(ha[s], ldb8(lb + (20+s)*512), hn,0,0,0);
    }
#pragma unroll
    for (int r=0;r<4;++r){
      const long rr = tbase + kq*4 + r;
      if (rr < NN){
        float rg = sigm(ar[r]+bir + hr[r]+bhr);
        float zg = sigm(az[r]+biz + hz[r]+bhz);
        float ng = tanh_(an[r]+bin + rg*(hn[r]+bhn));
        float u  = ng + zg*(h0p[r]-ng);
        unf32[rr*DIM+oc] = u;
        nfb[rr*DIM+oc] = f2b(u);   // safe: nfb reads preloaded before loop
      }
    }
    __syncthreads();
  }
}

extern "C" void kernel_launch(void* const* d_in, const int* in_sizes, int n_in,
                              void* d_out, int out_size, void* d_ws, size_t ws_size,
                              hipStream_t stream)
{
  const float* nf_in = (const float*)d_in[0];
  const float* ef_in = (const float*)d_in[1];
  const int*   src   = (const int*)d_in[2];
  const int*   dst   = (const int*)d_in[3];
  const float* eWih  = (const float*)d_in[4];
  const float* eWhh  = (const float*)d_in[5];
  const float* ebih  = (const float*)d_in[6];
  const float* ebhh  = (const float*)d_in[7];
  const float* nWih  = (const float*)d_in[8];
  const float* nWhh  = (const float*)d_in[9];
  const float* nbih  = (const float*)d_in[10];
  const float* nbhh  = (const float*)d_in[11];
  const float* aW1   = (const float*)d_in[12];
  const float* ab1   = (const float*)d_in[13];
  const float* aW2   = (const float*)d_in[14];
  const float* ab2   = (const float*)d_in[15];

  float* nf_out = (float*)d_out;
  float* ef_out = nf_out + (size_t)NN*DIM;

  // workspace carve (~135 MB)
  char* p = (char*)d_ws;
  auto carve = [&](size_t bytes)->void*{ void* r = (void*)p; p += (bytes + 255) & ~(size_t)255; return r; };
  u16* efb    = (u16*)carve((size_t)NE*DIM*2);      // permuted (CSR order) ef state
  u16* nfb    = (u16*)carve((size_t)NN*DIM*2);
  u16* aggb   = (u16*)carve((size_t)NN*DIM*2);
  float* logits = (float*)carve((size_t)NE*4);      // permuted order
  int* eids   = (int*)carve((size_t)NE*4);
  int* srcp   = (int*)carve((size_t)NE*4);
  int* dstp   = (int*)carve((size_t)NE*4);
  int* counts = (int*)carve((size_t)NN*4);
  int* rowp   = (int*)carve((size_t)(NN+1)*4);
  int* cursor = (int*)carve((size_t)NN*4);
  int* bsum   = (int*)carve((size_t)64*4);
  u16* bWih   = (u16*)carve((size_t)384*256*2);
  u16* bWhh   = (u16*)carve((size_t)384*128*2);
  u16* bnWih  = (u16*)carve((size_t)384*128*2);
  u16* bnWhh  = (u16*)carve((size_t)384*128*2);
  u16* baW1T  = (u16*)carve((size_t)128*128*2);

  const int NB = (NN + 1023)/1024;   // 49 scan blocks

  // CSR over dst + permutation (constant across iterations)
  hipMemsetAsync(counts, 0, (size_t)NN*4, stream);
  hist_kernel<<<(NE+255)/256,256,0,stream>>>(dst, counts, NE);
  scanA_kernel<<<NB,1024,0,stream>>>(counts, rowp, bsum, NN);
  scanB_kernel<<<1,64,0,stream>>>(bsum, rowp, NB, NN);
  scanC_kernel<<<NB,1024,0,stream>>>(rowp, cursor, bsum, NN);
  scatter_kernel<<<(NE+255)/256,256,0,stream>>>(dst, cursor, eids, NE);
  perm_kernel<<<(NE+255)/256,256,0,stream>>>(eids, src, dst, srcp, dstp, NE);

  // bf16 conversions (once per launch); ef ingested directly by edge it0
  f2b_kernel<<<2048,256,0,stream>>>(nf_in, nfb, NN*DIM/4);
  wprep_kernel<<<1024,256,0,stream>>>(eWih, eWhh, nWih, nWhh, aW1,
                                      bWih, bWhh, bnWih, bnWhh, baW1T);

  // ---- iteration 0: edge gathers+converts ef from fp32 input, seeds efb ----
  edge_kernel<true><<<NE/128,512,0,stream>>>(srcp, dstp, eids, nfb, efb, ef_in,
                                             bWih, bWhh, ebih, ebhh,
                                             baW1T, ab1, aW2, ab2, logits, nullptr);
  agg_kernel<<<(NN+3)/4,256,0,stream>>>(rowp, logits, efb, aggb);
  node_kernel<<<(NN+127)/128,512,0,stream>>>(aggb, nfb, nf_in, nf_out,
                                             bnWih, bnWhh, nbih, nbhh);
  // ---- iteration 1: edge reads bf16 efb state; writes fp32 ef_out ----
  edge_kernel<false><<<NE/128,512,0,stream>>>(srcp, dstp, eids, nfb, efb, nullptr,
                                              bWih, bWhh, ebih, ebhh,
                                              baW1T, ab1, aW2, ab2, logits, ef_out);
  agg_kernel<<<(NN+3)/4,256,0,stream>>>(rowp, logits, efb, aggb);
  node_kernel<<<(NN+127)/128,512,0,stream>>>(aggb, nfb, nf_out, nf_out,
                                             bnWih, bnWhh, nbih, nbhh);
}

// Round 18
// 764.426 us; speedup vs baseline: 1.0112x; 1.0112x over previous
//
#include <hip/hip_runtime.h>

#define NN 50000
#define NE 400000
#define DIM 128

typedef __bf16 bf16x8 __attribute__((ext_vector_type(8)));
typedef float f32x4 __attribute__((ext_vector_type(4)));
typedef unsigned short u16;

#define MFMA16 __builtin_amdgcn_mfma_f32_16x16x32_bf16

__device__ __forceinline__ u16 f2b(float f){ __bf16 b=(__bf16)f; return __builtin_bit_cast(u16,b); }
__device__ __forceinline__ float b2f(u16 h){ unsigned u = ((unsigned)h)<<16; return __builtin_bit_cast(float,u); }
__device__ __forceinline__ float sigm(float x){ return 1.0f/(1.0f+__expf(-x)); }
__device__ __forceinline__ float tanh_(float x){ float e=__expf(2.0f*x); return 1.0f-2.0f/(e+1.0f); }
__device__ __forceinline__ bf16x8 ldb8(const u16* p){ return *reinterpret_cast<const bf16x8*>(p); }

#define GLOAD_LDS(gp, lp) __builtin_amdgcn_global_load_lds( \
    (const __attribute__((address_space(1))) void*)(gp),    \
    (__attribute__((address_space(3))) void*)(lp), 16, 0, 0)

// ---------- utility kernels ----------
__global__ void f2b_kernel(const float* __restrict__ in, u16* __restrict__ out, int n4){
  int i = blockIdx.x*blockDim.x + threadIdx.x;
  int st = gridDim.x*blockDim.x;
  for (; i<n4; i+=st){
    float4 v = reinterpret_cast<const float4*>(in)[i];
    ushort4 o = { f2b(v.x), f2b(v.y), f2b(v.z), f2b(v.w) };
    reinterpret_cast<ushort4*>(out)[i] = o;
  }
}

// fused weight prep: all 4 GRU weight converts + aW1 transpose in one launch
__global__ void wprep_kernel(const float* __restrict__ eWih, const float* __restrict__ eWhh,
                             const float* __restrict__ nWih, const float* __restrict__ nWhh,
                             const float* __restrict__ aW1,
                             u16* __restrict__ bWih, u16* __restrict__ bWhh,
                             u16* __restrict__ bnWih, u16* __restrict__ bnWhh,
                             u16* __restrict__ baW1T){
  int i = blockIdx.x*256 + threadIdx.x;        // 1024 blocks x 256 = 262144
  if (i < 98304){ bWih[i] = f2b(eWih[i]); return; }
  i -= 98304;
  if (i < 49152){ bWhh[i] = f2b(eWhh[i]); return; }
  i -= 49152;
  if (i < 49152){ bnWih[i] = f2b(nWih[i]); return; }
  i -= 49152;
  if (i < 49152){ bnWhh[i] = f2b(nWhh[i]); return; }
  i -= 49152;
  { int k = i>>7, n = i&127; baW1T[n*128+k] = f2b(aW1[i]); }
}

__global__ void hist_kernel(const int* __restrict__ dst, int* __restrict__ counts, int n){
  int i = blockIdx.x*blockDim.x + threadIdx.x; if (i<n) atomicAdd(&counts[dst[i]],1);
}
// parallel exclusive scan over counts -> rowp/cursor (3 phases)
__global__ void scanA_kernel(const int* __restrict__ counts, int* __restrict__ rowp,
                             int* __restrict__ bsum, int n){
  __shared__ int buf[1024];
  const int gid = blockIdx.x*1024 + threadIdx.x;
  int v = (gid<n) ? counts[gid] : 0;
  buf[threadIdx.x]=v; __syncthreads();
  for (int off=1; off<1024; off<<=1){
    int x = (threadIdx.x>=off) ? buf[threadIdx.x-off] : 0;
    __syncthreads();
    buf[threadIdx.x]+=x; __syncthreads();
  }
  if (gid<n) rowp[gid] = buf[threadIdx.x]-v;          // block-local exclusive
  if (threadIdx.x==1023) bsum[blockIdx.x]=buf[1023];  // block total
}
__global__ void scanB_kernel(int* bsum, int* rowp, int nb, int n){
  if (threadIdx.x==0 && blockIdx.x==0){
    int run=0;
    for (int b=0;b<nb;++b){ int t=bsum[b]; bsum[b]=run; run+=t; }
    rowp[n]=run;
  }
}
__global__ void scanC_kernel(int* __restrict__ rowp, int* __restrict__ cursor,
                             const int* __restrict__ bsum, int n){
  const int gid = blockIdx.x*1024 + threadIdx.x;
  if (gid<n){ int v = rowp[gid]+bsum[blockIdx.x]; rowp[gid]=v; cursor[gid]=v; }
}
__global__ void scatter_kernel(const int* __restrict__ dst, int* __restrict__ cursor,
                               int* __restrict__ eids, int n){
  int i = blockIdx.x*blockDim.x + threadIdx.x;
  if (i<n){ int p = atomicAdd(&cursor[dst[i]],1); eids[p]=i; }
}
// permuted edge endpoints (CSR order by dst)
__global__ void perm_kernel(const int* __restrict__ eids, const int* __restrict__ src,
                            const int* __restrict__ dst, int* __restrict__ srcp,
                            int* __restrict__ dstp, int n){
  int i = blockIdx.x*blockDim.x + threadIdx.x;
  if (i<n){ int e=eids[i]; srcp[i]=src[e]; dstp[i]=dst[e]; }
}

// ---------- edge GRU + attention MLP (v18 == v16, best measured: 766us total) ----------
// v12 hot-loop (converged optimum: 294us it1): 512 thr = 8 waves x 16 edges,
// single 36KB frag-major weight buffer, 2-barrier chunk loop, launch_bounds(512,4).
// Template<IT0>: it0 reads ef directly from fp32 ef_in (original order via eids)
// -- ae gathered+converted once, h0 scattered fp32 (L3-resident) -- deleting the
// separate efgather pass. v17's seed-write variant regressed (stores are
// write-through/no-allocate -> h0 re-reads hit L2 with store dependency).
// Design-space closure (rounds 4-17): every structural deviation regresses;
// constraint set = {A-frag VGPR floor 48 -> 64-VGPR alloc -> 16 waves/CU,
// LDS-mandatory weight staging, 18 barrier drains partially overlapped}.
template<bool IT0>
__global__ __launch_bounds__(512, 4)
void edge_kernel(const int* __restrict__ srcp, const int* __restrict__ dstp,
                 const int* __restrict__ eids,
                 const u16* __restrict__ nfb, u16* __restrict__ efb,
                 const float* __restrict__ ef32in,
                 const u16* __restrict__ Wih, const u16* __restrict__ Whh,
                 const float* __restrict__ bih, const float* __restrict__ bhh,
                 const u16* __restrict__ aW1T, const float* __restrict__ ab1,
                 const float* __restrict__ aW2, const float* __restrict__ ab2,
                 float* __restrict__ logits, float* __restrict__ ef32out)
{
  __shared__ __align__(16) u16 wbuf[36*512];   // 36 KB, frag-major
  const int wave = threadIdx.x>>6, lane = threadIdx.x&63;
  const int r16 = lane&15, kq = lane>>4;
  const long base = (long)blockIdx.x*128 + wave*16;
  const long e = base + r16;

  // cooperative staging of chunk c's weight frags (c=8 -> attention weights)
  auto stage = [&](int c){
    if (c < 8){
      for (int f = wave; f < 36; f += 8){
        const u16* g;
        if (f < 24){ const int gt = f>>3, s = f&7;
          g = Wih + (long)(gt*128 + c*16 + r16)*256 + s*32 + kq*8; }
        else { const int q = f-24, gt = q>>2, s = q&3;
          g = Whh + (long)(gt*128 + c*16 + r16)*128 + s*32 + kq*8; }
        GLOAD_LDS(g, wbuf + f*512);
      }
    } else {
      for (int f = wave; f < 32; f += 8){
        const int t = f>>2, s = f&3;
        GLOAD_LDS(aW1T + (long)(t*16 + r16)*128 + s*32 + kq*8, wbuf + f*512);
      }
    }
  };

  // A-fragments, loaded ONCE into registers: gi K=256 (src|dst), gh K=128 (ef)
  const u16* sp = nfb + (long)srcp[e]*DIM;
  const u16* dp = nfb + (long)dstp[e]*DIM;
  const u16* ep = efb + e*DIM;
  bf16x8 ag[8], ae[4];
#pragma unroll
  for (int s=0;s<4;++s){
    ag[s]   = ldb8(sp + s*32 + kq*8);
    ag[s+4] = ldb8(dp + s*32 + kq*8);
  }
  if (IT0){
    const float* epf = ef32in + (long)eids[e]*DIM;
#pragma unroll
    for (int s=0;s<4;++s){
      float4 f0 = *reinterpret_cast<const float4*>(epf + s*32 + kq*8);
      float4 f1 = *reinterpret_cast<const float4*>(epf + s*32 + kq*8 + 4);
      bf16x8 t;
      t[0]=(__bf16)f0.x; t[1]=(__bf16)f0.y; t[2]=(__bf16)f0.z; t[3]=(__bf16)f0.w;
      t[4]=(__bf16)f1.x; t[5]=(__bf16)f1.y; t[6]=(__bf16)f1.z; t[7]=(__bf16)f1.w;
      ae[s] = t;
    }
  } else {
#pragma unroll
    for (int s=0;s<4;++s) ae[s] = ldb8(ep + s*32 + kq*8);
  }
  // original edge ids for the 4 rows this lane epilogues
  int oe[4];
#pragma unroll
  for (int r=0;r<4;++r) oe[r] = eids[base + kq*4 + r];

  stage(0);
  __syncthreads();

  // hoisted bases: all epilogue accesses are base + r*DIM + c*16 (imm-friendly)
  u16* ebase = efb + (base + kq*4)*DIM + r16;
  const float* bi0 = bih + r16;
  const float* bh0 = bhh + r16;

  const f32x4 vzero = {0.f,0.f,0.f,0.f};
  const u16* lbase = wbuf + lane*8;   // frag f => lbase + f*512 (u16 units)

#pragma unroll 1
  for (int c=0;c<8;++c){
    const int c16 = c*16;
    const float bir=bi0[c16], biz=bi0[c16+DIM], bin=bi0[c16+2*DIM];
    const float bhr=bh0[c16], bhz=bh0[c16+DIM], bhn=bh0[c16+2*DIM];
    float h0p[4];
    if (IT0){
#pragma unroll
      for (int r=0;r<4;++r) h0p[r] = ef32in[(long)oe[r]*DIM + c16 + r16];  // L3-hot
    } else {
#pragma unroll
      for (int r=0;r<4;++r) h0p[r] = b2f(ebase[r*DIM + c16]);             // L1/L2-hot
    }

    f32x4 ar=vzero, az=vzero, an=vzero, hr=vzero, hz=vzero, hn=vzero;
#pragma unroll
    for (int s=0;s<8;++s){
      ar = MFMA16(ag[s], ldb8(lbase + ( s   )*512), ar,0,0,0);
      az = MFMA16(ag[s], ldb8(lbase + ( 8+s )*512), az,0,0,0);
      an = MFMA16(ag[s], ldb8(lbase + (16+s )*512), an,0,0,0);
    }
#pragma unroll
    for (int s=0;s<4;++s){
      hr = MFMA16(ae[s], ldb8(lbase + (24+s)*512), hr,0,0,0);
      hz = MFMA16(ae[s], ldb8(lbase + (28+s)*512), hz,0,0,0);
      hn = MFMA16(ae[s], ldb8(lbase + (32+s)*512), hn,0,0,0);
    }
    __syncthreads();              // all waves done reading wbuf
    stage(c+1);                   // refill; drains at end-of-chunk barrier
    float uv[4];
#pragma unroll
    for (int r=0;r<4;++r){
      float rg = sigm(ar[r]+bir + hr[r]+bhr);
      float zg = sigm(az[r]+biz + hz[r]+bhz);
      float ng = tanh_(an[r]+bin + rg*(hn[r]+bhn));
      float u  = ng + zg*(h0p[r]-ng);
      ebase[r*DIM + c16] = f2b(u);
      uv[r] = u;
    }
    if (ef32out){
#pragma unroll
      for (int r=0;r<4;++r) ef32out[(long)oe[r]*DIM + c16 + r16] = uv[r];
    }
    __syncthreads();              // wbuf refilled; stores drained
  }

  // ----- attention MLP: chunk 8 (aW1T) in wbuf; uef row re-read L1-hot -----
  bf16x8 ua[4];
#pragma unroll
  for (int s=0;s<4;++s) ua[s] = ldb8(ep + s*32 + kq*8);
  float part[4] = {0.f,0.f,0.f,0.f};
#pragma unroll 1
  for (int t=0;t<8;++t){
    f32x4 h = vzero;
#pragma unroll
    for (int s=0;s<4;++s)
      h = MFMA16(ua[s], ldb8(lbase + (t*4+s)*512), h,0,0,0);
    const int cc = t*16 + r16;
    const float b1 = ab1[cc], w2 = aW2[cc];
#pragma unroll
    for (int r=0;r<4;++r) part[r] += fmaxf(h[r]+b1, 0.f)*w2;
  }
#pragma unroll
  for (int off=1; off<16; off<<=1){
#pragma unroll
    for (int r=0;r<4;++r) part[r] += __shfl_xor(part[r], off, 64);
  }
  if (r16==0){
    const float b2v = ab2[0];
#pragma unroll
    for (int r=0;r<4;++r) logits[base + kq*4 + r] = part[r] + b2v;   // sequential
  }
}

// ---------- softmax + weighted aggregation (permuted CSR: fully sequential) ----------
__global__ __launch_bounds__(256)
void agg_kernel(const int* __restrict__ rowp, const float* __restrict__ logits,
                const u16* __restrict__ uefb, u16* __restrict__ aggb)
{
  const int wave = threadIdx.x>>6, lane = threadIdx.x&63;
  const int v = blockIdx.x*4 + wave;
  if (v>=NN) return;
  const int p0 = rowp[v], p1 = rowp[v+1], deg = p1-p0;
  float ax=0.f, ay=0.f;
  if (deg>0){
    float mx = -__builtin_inff();
    for (int i=p0+lane; i<p1; i+=64) mx = fmaxf(mx, logits[i]);
#pragma unroll
    for (int off=32; off; off>>=1) mx = fmaxf(mx, __shfl_xor(mx, off, 64));
    float ss = 0.f;
    for (int i=p0+lane; i<p1; i+=64) ss += __expf(logits[i] - mx);
#pragma unroll
    for (int off=32; off; off>>=1) ss += __shfl_xor(ss, off, 64);
    const float inv = 1.0f/ss;
    int i = p0;
    for (; i+2<=p1; i+=2){
      const float l0 = logits[i], l1 = logits[i+1];
      const unsigned q0 = *reinterpret_cast<const unsigned*>(uefb + (long)i*DIM + lane*2);
      const unsigned q1 = *reinterpret_cast<const unsigned*>(uefb + (long)(i+1)*DIM + lane*2);
      const float a0 = __expf(l0-mx)*inv, a1 = __expf(l1-mx)*inv;
      ax += a0*b2f((u16)q0) + a1*b2f((u16)q1);
      ay += a0*b2f((u16)(q0>>16)) + a1*b2f((u16)(q1>>16));
    }
    if (i<p1){
      const float a0 = __expf(logits[i]-mx)*inv;
      const unsigned q0 = *reinterpret_cast<const unsigned*>(uefb + (long)i*DIM + lane*2);
      ax += a0*b2f((u16)q0);
      ay += a0*b2f((u16)(q0>>16));
    }
  }
  unsigned pack = (unsigned)f2b(ax) | ((unsigned)f2b(ay)<<16);
  *reinterpret_cast<unsigned*>(aggb + (long)v*DIM + lane*2) = pack;
}

// ---------- node GRU (double-buffered staged weights, 8 waves x 16 nodes) ----------
__global__ __launch_bounds__(512, 4)
void node_kernel(const u16* __restrict__ aggb, u16* __restrict__ nfb,
                 const float* nf32, float* unf32,            // may alias (in-place iter 2)
                 const u16* __restrict__ Wih, const u16* __restrict__ Whh,
                 const float* __restrict__ bih, const float* __restrict__ bhh)
{
  __shared__ __align__(16) u16 wbuf[2*24*512];   // 48 KB, frag-major, double-buffered
  const int wave = threadIdx.x>>6, lane = threadIdx.x&63;
  const int r16 = lane&15, kq = lane>>4;
  const long tbase = (long)blockIdx.x*128 + wave*16;
  const long v = tbase + r16;
  const long vcl = (v < NN) ? v : (NN-1);

  auto stage = [&](int c){
    if (c >= 8) return;
    u16* bufp = wbuf + (c&1)*24*512;
    for (int f = wave; f < 24; f += 8){
      const u16* g;
      if (f < 12){ const int gt = f>>2, s = f&3;
        g = Wih + (long)(gt*128 + c*16 + r16)*128 + s*32 + kq*8; }
      else { const int q = f-12, gt = q>>2, s = q&3;
        g = Whh + (long)(gt*128 + c*16 + r16)*128 + s*32 + kq*8; }
      GLOAD_LDS(g, bufp + f*512);
    }
  };

  bf16x8 xa[4], ha[4];
#pragma unroll
  for (int s=0;s<4;++s){
    xa[s] = ldb8(aggb + vcl*DIM + s*32 + kq*8);
    ha[s] = ldb8(nfb  + vcl*DIM + s*32 + kq*8);
  }
  stage(0);
  __syncthreads();

  const f32x4 vzero = {0.f,0.f,0.f,0.f};

#pragma unroll 1
  for (int c=0;c<8;++c){
    stage(c+1);
    const int oc = c*16 + r16;
    const float bir=bih[oc], biz=bih[DIM+oc], bin=bih[2*DIM+oc];
    const float bhr=bhh[oc], bhz=bhh[DIM+oc], bhn=bhh[2*DIM+oc];
    float h0p[4];
#pragma unroll
    for (int r=0;r<4;++r){
      const long rr = tbase + kq*4 + r;
      h0p[r] = (rr < NN) ? nf32[rr*DIM+oc] : 0.f;
    }
    const u16* lb = wbuf + (c&1)*24*512 + lane*8;
    f32x4 ar=vzero, az=vzero, an=vzero, hr=vzero, hz=vzero, hn=vzero;
#pragma unroll
    for (int s=0;s<4;++s){
      ar=MFMA16(xa[s], ldb8(lb + ( s   )*512), ar,0,0,0);
      az=MFMA16(xa[s], ldb8(lb + ( 4+s)*512), az,0,0,0);
      an=MFMA16(xa[s], ldb8(lb + ( 8+s)*512), an,0,0,0);
      hr=MFMA16(ha[s], ldb8(lb + (12+s)*512), hr,0,0,0);
      hz=MFMA16(ha[s], ldb8(lb + (16+s)*512), hz,0,0,0);
      hn=MFMA16(ha[s], ldb8(lb + (20+s)*512), hn,0,0,0);
    }
#pragma unroll
    for (int r=0;r<4;++r){
      const long rr = tbase + kq*4 + r;
      if (rr < NN){
        float rg = sigm(ar[r]+bir + hr[r]+bhr);
        float zg = sigm(az[r]+biz + hz[r]+bhz);
        float ng = tanh_(an[r]+bin + rg*(hn[r]+bhn));
        float u  = ng + zg*(h0p[r]-ng);
        unf32[rr*DIM+oc] = u;
        nfb[rr*DIM+oc] = f2b(u);   // safe: nfb reads preloaded before loop
      }
    }
    __syncthreads();
  }
}

extern "C" void kernel_launch(void* const* d_in, const int* in_sizes, int n_in,
                              void* d_out, int out_size, void* d_ws, size_t ws_size,
                              hipStream_t stream)
{
  const float* nf_in = (const float*)d_in[0];
  const float* ef_in = (const float*)d_in[1];
  const int*   src   = (const int*)d_in[2];
  const int*   dst   = (const int*)d_in[3];
  const float* eWih  = (const float*)d_in[4];
  const float* eWhh  = (const float*)d_in[5];
  const float* ebih  = (const float*)d_in[6];
  const float* ebhh  = (const float*)d_in[7];
  const float* nWih  = (const float*)d_in[8];
  const float* nWhh  = (const float*)d_in[9];
  const float* nbih  = (const float*)d_in[10];
  const float* nbhh  = (const float*)d_in[11];
  const float* aW1   = (const float*)d_in[12];
  const float* ab1   = (const float*)d_in[13];
  const float* aW2   = (const float*)d_in[14];
  const float* ab2   = (const float*)d_in[15];

  float* nf_out = (float*)d_out;
  float* ef_out = nf_out + (size_t)NN*DIM;

  // workspace carve (~135 MB)
  char* p = (char*)d_ws;
  auto carve = [&](size_t bytes)->void*{ void* r = (void*)p; p += (bytes + 255) & ~(size_t)255; return r; };
  u16* efb    = (u16*)carve((size_t)NE*DIM*2);      // permuted (CSR order) ef state
  u16* nfb    = (u16*)carve((size_t)NN*DIM*2);
  u16* aggb   = (u16*)carve((size_t)NN*DIM*2);
  float* logits = (float*)carve((size_t)NE*4);      // permuted order
  int* eids   = (int*)carve((size_t)NE*4);
  int* srcp   = (int*)carve((size_t)NE*4);
  int* dstp   = (int*)carve((size_t)NE*4);
  int* counts = (int*)carve((size_t)NN*4);
  int* rowp   = (int*)carve((size_t)(NN+1)*4);
  int* cursor = (int*)carve((size_t)NN*4);
  int* bsum   = (int*)carve((size_t)64*4);
  u16* bWih   = (u16*)carve((size_t)384*256*2);
  u16* bWhh   = (u16*)carve((size_t)384*128*2);
  u16* bnWih  = (u16*)carve((size_t)384*128*2);
  u16* bnWhh  = (u16*)carve((size_t)384*128*2);
  u16* baW1T  = (u16*)carve((size_t)128*128*2);

  const int NB = (NN + 1023)/1024;   // 49 scan blocks

  // CSR over dst + permutation (constant across iterations)
  hipMemsetAsync(counts, 0, (size_t)NN*4, stream);
  hist_kernel<<<(NE+255)/256,256,0,stream>>>(dst, counts, NE);
  scanA_kernel<<<NB,1024,0,stream>>>(counts, rowp, bsum, NN);
  scanB_kernel<<<1,64,0,stream>>>(bsum, rowp, NB, NN);
  scanC_kernel<<<NB,1024,0,stream>>>(rowp, cursor, bsum, NN);
  scatter_kernel<<<(NE+255)/256,256,0,stream>>>(dst, cursor, eids, NE);
  perm_kernel<<<(NE+255)/256,256,0,stream>>>(eids, src, dst, srcp, dstp, NE);

  // bf16 conversions (once per launch); ef ingested directly by edge it0
  f2b_kernel<<<2048,256,0,stream>>>(nf_in, nfb, NN*DIM/4);
  wprep_kernel<<<1024,256,0,stream>>>(eWih, eWhh, nWih, nWhh, aW1,
                                      bWih, bWhh, bnWih, bnWhh, baW1T);

  // ---- iteration 0: edge reads ef from fp32 input (fused gather+convert) ----
  edge_kernel<true><<<NE/128,512,0,stream>>>(srcp, dstp, eids, nfb, efb, ef_in,
                                             bWih, bWhh, ebih, ebhh,
                                             baW1T, ab1, aW2, ab2, logits, nullptr);
  agg_kernel<<<(NN+3)/4,256,0,stream>>>(rowp, logits, efb, aggb);
  node_kernel<<<(NN+127)/128,512,0,stream>>>(aggb, nfb, nf_in, nf_out,
                                             bnWih, bnWhh, nbih, nbhh);
  // ---- iteration 1: edge reads bf16 efb state; writes fp32 ef_out ----
  edge_kernel<false><<<NE/128,512,0,stream>>>(srcp, dstp, eids, nfb, efb, nullptr,
                                              bWih, bWhh, ebih, ebhh,
                                              baW1T, ab1, aW2, ab2, logits, ef_out);
  agg_kernel<<<(NN+3)/4,256,0,stream>>>(rowp, logits, efb, aggb);
  node_kernel<<<(NN+127)/128,512,0,stream>>>(aggb, nfb, nf_out, nf_out,
                                             bnWih, bnWhh, nbih, nbhh);
}